// Round 4
// baseline (133.015 us; speedup 1.0000x reference)
//
#include <hip/hip_runtime.h>

// MaxAbsPool2D: x (32,224,224,96) f32 NHWC, pool 2x2 -> out (32,112,112,96).
// Select the signed value with max |.| in each 2x2 window per channel,
// first-index-wins on ties (match jnp.argmax).
//
// R3: unroll 2 output float4 per thread (block-strided pair e, e+256 so every
//     load stays wave-contiguous) -> 8 nt-loads in flight, half the per-byte
//     instruction overhead. Grid 18816x256 exact, no bounds checks.

#define B_  32
#define H_  224
#define W_  224
#define C_  96
#define HO_ 112
#define WO_ 112
#define C4_ (C_ / 4)             // 24 float4 per pixel
#define ROWSTRIDE (W_ * C_)      // 21504 floats

typedef float f32x4 __attribute__((ext_vector_type(4)));

__device__ __forceinline__ float sel4(float v0, float v1, float v2, float v3) {
    float v  = v0;
    float av = fabsf(v0);
    float a1 = fabsf(v1);
    if (a1 > av) { v = v1; av = a1; }
    float a2 = fabsf(v2);
    if (a2 > av) { v = v2; av = a2; }
    float a3 = fabsf(v3);
    if (a3 > av) { v = v3; }
    return v;
}

__device__ __forceinline__ f32x4 ntload4(const float* p) {
    return __builtin_nontemporal_load((const f32x4*)p);
}

__device__ __forceinline__ const float* in_ptr(int e) {
    int c4  = e % C4_;
    int pix = e / C4_;
    int wo  = pix % WO_;
    int t   = pix / WO_;
    int ho  = t % HO_;
    int b   = t / HO_;
    return (const float*)0 + ((size_t)((b * H_ + 2 * ho) * W_ + 2 * wo) * C_ + c4 * 4);
}

__global__ void __launch_bounds__(256)
maxabspool_kernel(const float* __restrict__ x, float* __restrict__ out) {
    int e0 = blockIdx.x * 512 + threadIdx.x;  // exact: grid*512 == total4
    int e1 = e0 + 256;

    const float* p0 = x + (size_t)(in_ptr(e0) - (const float*)0);
    const float* p1 = x + (size_t)(in_ptr(e1) - (const float*)0);

    f32x4 a00 = ntload4(p0);
    f32x4 a01 = ntload4(p0 + C_);
    f32x4 a10 = ntload4(p0 + ROWSTRIDE);
    f32x4 a11 = ntload4(p0 + ROWSTRIDE + C_);

    f32x4 b00 = ntload4(p1);
    f32x4 b01 = ntload4(p1 + C_);
    f32x4 b10 = ntload4(p1 + ROWSTRIDE);
    f32x4 b11 = ntload4(p1 + ROWSTRIDE + C_);

    f32x4 r0, r1;
    r0.x = sel4(a00.x, a01.x, a10.x, a11.x);
    r0.y = sel4(a00.y, a01.y, a10.y, a11.y);
    r0.z = sel4(a00.z, a01.z, a10.z, a11.z);
    r0.w = sel4(a00.w, a01.w, a10.w, a11.w);

    r1.x = sel4(b00.x, b01.x, b10.x, b11.x);
    r1.y = sel4(b00.y, b01.y, b10.y, b11.y);
    r1.z = sel4(b00.z, b01.z, b10.z, b11.z);
    r1.w = sel4(b00.w, b01.w, b10.w, b11.w);

    __builtin_nontemporal_store(r0, (f32x4*)(out + (size_t)e0 * 4));
    __builtin_nontemporal_store(r1, (f32x4*)(out + (size_t)e1 * 4));
}

extern "C" void kernel_launch(void* const* d_in, const int* in_sizes, int n_in,
                              void* d_out, int out_size, void* d_ws, size_t ws_size,
                              hipStream_t stream) {
    const float* x = (const float*)d_in[0];
    float* out = (float*)d_out;

    const int total4 = out_size / 4;          // 9,633,792
    const int block  = 256;
    const int grid   = total4 / (block * 2);  // 18816, exact

    maxabspool_kernel<<<grid, block, 0, stream>>>(x, out);
}

// Round 5
// 130.011 us; speedup vs baseline: 1.0231x; 1.0231x over previous
//
#include <hip/hip_runtime.h>

// MaxAbsPool2D: x (32,224,224,96) f32 NHWC, pool 2x2 -> out (32,112,112,96).
// Select the signed value with max |.| in each 2x2 window per channel,
// first-index-wins on ties (match jnp.argmax).
//
// R4: revert to R2 form (best @130.2us = 5.92 TB/s, 94% of measured copy
//     ceiling). R3's 2x unroll regressed (+2.2%): MLP was not the limiter.
//     One float4 per thread, exact grid 37632x256, nt loads/stores.

#define B_  32
#define H_  224
#define W_  224
#define C_  96
#define HO_ 112
#define WO_ 112
#define C4_ (C_ / 4)             // 24 float4 per pixel
#define ROWSTRIDE (W_ * C_)      // 21504 floats

typedef float f32x4 __attribute__((ext_vector_type(4)));

__device__ __forceinline__ float sel4(float v0, float v1, float v2, float v3) {
    float v  = v0;
    float av = fabsf(v0);
    float a1 = fabsf(v1);
    if (a1 > av) { v = v1; av = a1; }
    float a2 = fabsf(v2);
    if (a2 > av) { v = v2; av = a2; }
    float a3 = fabsf(v3);
    if (a3 > av) { v = v3; }
    return v;
}

__device__ __forceinline__ f32x4 ntload4(const float* p) {
    return __builtin_nontemporal_load((const f32x4*)p);
}

__global__ void __launch_bounds__(256)
maxabspool_kernel(const float* __restrict__ x, float* __restrict__ out) {
    int e = blockIdx.x * 256 + threadIdx.x;   // exact: grid*256 == total4

    int c4  = e % C4_;
    int pix = e / C4_;
    int wo  = pix % WO_;
    int t   = pix / WO_;
    int ho  = t % HO_;
    int b   = t / HO_;

    const float* p0 = x + ((size_t)((b * H_ + 2 * ho) * W_ + 2 * wo) * C_ + c4 * 4);

    f32x4 q00 = ntload4(p0);                  // (dy=0, dx=0)
    f32x4 q01 = ntload4(p0 + C_);             // (dy=0, dx=1)
    f32x4 q10 = ntload4(p0 + ROWSTRIDE);      // (dy=1, dx=0)
    f32x4 q11 = ntload4(p0 + ROWSTRIDE + C_); // (dy=1, dx=1)

    f32x4 r;
    r.x = sel4(q00.x, q01.x, q10.x, q11.x);
    r.y = sel4(q00.y, q01.y, q10.y, q11.y);
    r.z = sel4(q00.z, q01.z, q10.z, q11.z);
    r.w = sel4(q00.w, q01.w, q10.w, q11.w);

    __builtin_nontemporal_store(r, (f32x4*)(out + (size_t)e * 4));
}

extern "C" void kernel_launch(void* const* d_in, const int* in_sizes, int n_in,
                              void* d_out, int out_size, void* d_ws, size_t ws_size,
                              hipStream_t stream) {
    const float* x = (const float*)d_in[0];
    float* out = (float*)d_out;

    const int total4 = out_size / 4;          // 9,633,792
    const int block  = 256;
    const int grid   = total4 / block;        // 37632, exact

    maxabspool_kernel<<<grid, block, 0, stream>>>(x, out);
}